// Round 4
// baseline (414.288 us; speedup 1.0000x reference)
//
#include <hip/hip_runtime.h>

#define HW    1024
#define C_CH  512

typedef __attribute__((ext_vector_type(8)))  short bfrag;    // 8 bf16 = 4 VGPR (MFMA A/B operand)
typedef __attribute__((ext_vector_type(16))) float f32x16;   // MFMA 32x32 accumulator

// ws layout (floats): S[8][4096] @0 (fully written by reduce, no zeroing),
//                     chansum[512] @32768 (zeroed), v0f[512] @33280,
//                     w2[512] @33792, b2[512] @34304
// d_out doubles as scratch for cov partial tiles: Spart[512][4096] (8.4 MB),
// consumed by reduce_kernel BEFORE apply_kernel overwrites d_out.

// ---------------------------------------------------------------------------
// K1: per-(g,n) Gram of a 64ch x 1024hw slab via split-bf16 MFMA.
// fp32 x = hi + lo (both RNE bf16; lo residual exact by Sterbenz); G sums 4
// passes hh+hl+lh+ll of mfma_f32_32x32x16_bf16 -> ~1e-5-accurate fp32 Gram
// on the matrix pipe. For a Gram the A-frag and B-frag of the same data are
// the same registers (row=lane&31, k=8*(lane>>5)+e), so 4 ds_read_b128 feed
// 16 MFMAs per k-step; any k-permutation cancels.
// 512 blocks x 256 thr; 4 waves split K (k-steps 2 per wave per chunk).
// 8 chunks x 128 cols; 32 KB LDS (bf16 hi+lo), 16B-slot XOR swizzle
// slot^(row&7): stage-writes and frag-reads both at the 1KB/wave LDS floor.
// T14: next chunk's 8 float4/thread global loads issue before the MFMA phase.
// Epilogue: 2-stage in-place LDS fold of the 4 wave-partials (fits 32 KB).
// ---------------------------------------------------------------------------
__global__ __launch_bounds__(256, 2) void cov_kernel(const float* __restrict__ x,
                                                     float* __restrict__ Spart,
                                                     float* __restrict__ chansum) {
  const int n = blockIdx.x & 63;
  const int g = blockIdx.x >> 6;
  __shared__ __align__(16) unsigned short LDSbuf[2 * 64 * 128];  // 32 KB
  unsigned short* Ahi = LDSbuf;
  unsigned short* Alo = LDSbuf + 64 * 128;

  const int t   = threadIdx.x;
  const int row = t >> 2;    // staging channel 0..63
  const int kq  = t & 3;     // staging col-quarter within a 128-col chunk
  const int l   = t & 63;    // lane
  const int w   = t >> 6;    // wave

  const float* rowp = x + ((size_t)(n * C_CH + g * 64) + row) * HW + kq * 32;

  f32x16 acc00 = {}, acc01 = {}, acc10 = {}, acc11 = {};
  float psum = 0.f;
  float4 buf0[8], buf1[8];

  auto LOADC = [&](float4* buf, int c) {
#pragma unroll
    for (int i = 0; i < 8; i++)
      buf[i] = *(const float4*)(rowp + c * 128 + 4 * i);
  };

  auto CVTW = [&](const float4* buf) {
#pragma unroll
    for (int p = 0; p < 4; p++) {
      const float xs[8] = {buf[2 * p].x, buf[2 * p].y, buf[2 * p].z, buf[2 * p].w,
                           buf[2 * p + 1].x, buf[2 * p + 1].y, buf[2 * p + 1].z, buf[2 * p + 1].w};
      unsigned int hu[8], lw[8];
#pragma unroll
      for (int e = 0; e < 8; e++) {
        const float xv = xs[e];
        const unsigned int u  = __float_as_uint(xv);
        const unsigned int r  = u + 0x7FFFu + ((u >> 16) & 1u);   // RNE to bf16
        const unsigned int hb = r & 0xFFFF0000u;
        const float lof = xv - __uint_as_float(hb);               // exact (Sterbenz)
        const unsigned int v  = __float_as_uint(lof);
        const unsigned int lr = v + 0x7FFFu + ((v >> 16) & 1u);   // RNE to bf16
        hu[e] = hb >> 16;
        lw[e] = lr >> 16;
        psum += xv;
      }
      uint4 hp, lp;
      hp.x = hu[0] | (hu[1] << 16); hp.y = hu[2] | (hu[3] << 16);
      hp.z = hu[4] | (hu[5] << 16); hp.w = hu[6] | (hu[7] << 16);
      lp.x = lw[0] | (lw[1] << 16); lp.y = lw[2] | (lw[3] << 16);
      lp.z = lw[4] | (lw[5] << 16); lp.w = lw[6] | (lw[7] << 16);
      const int slot = (kq * 4 + p) ^ (row & 7);  // 16 slots/row, XOR-swizzled
      *(uint4*)&Ahi[row * 128 + slot * 8] = hp;
      *(uint4*)&Alo[row * 128 + slot * 8] = lp;
    }
  };

  auto COMPUTE = [&]() {
#pragma unroll
    for (int k4 = 0; k4 < 2; k4++) {
      const int kl = w * 2 + k4;                // local k-step 0..7 (16 k each)
      const int sp = kl * 2 + (l >> 5);         // 16B slot index along k, 0..15
      const int r0 = l & 31;
      const int ph = sp ^ (r0 & 7);             // (32+r0)&7 == r0&7
      const int i0 = r0 * 128 + ph * 8;
      const int i1 = (32 + r0) * 128 + ph * 8;
      const bfrag hA0 = *(const bfrag*)&Ahi[i0];
      const bfrag hA1 = *(const bfrag*)&Ahi[i1];
      const bfrag lA0 = *(const bfrag*)&Alo[i0];
      const bfrag lA1 = *(const bfrag*)&Alo[i1];
      acc00 = __builtin_amdgcn_mfma_f32_32x32x16_bf16(hA0, hA0, acc00, 0, 0, 0);
      acc00 = __builtin_amdgcn_mfma_f32_32x32x16_bf16(hA0, lA0, acc00, 0, 0, 0);
      acc00 = __builtin_amdgcn_mfma_f32_32x32x16_bf16(lA0, hA0, acc00, 0, 0, 0);
      acc00 = __builtin_amdgcn_mfma_f32_32x32x16_bf16(lA0, lA0, acc00, 0, 0, 0);
      acc01 = __builtin_amdgcn_mfma_f32_32x32x16_bf16(hA0, hA1, acc01, 0, 0, 0);
      acc01 = __builtin_amdgcn_mfma_f32_32x32x16_bf16(hA0, lA1, acc01, 0, 0, 0);
      acc01 = __builtin_amdgcn_mfma_f32_32x32x16_bf16(lA0, hA1, acc01, 0, 0, 0);
      acc01 = __builtin_amdgcn_mfma_f32_32x32x16_bf16(lA0, lA1, acc01, 0, 0, 0);
      acc10 = __builtin_amdgcn_mfma_f32_32x32x16_bf16(hA1, hA0, acc10, 0, 0, 0);
      acc10 = __builtin_amdgcn_mfma_f32_32x32x16_bf16(hA1, lA0, acc10, 0, 0, 0);
      acc10 = __builtin_amdgcn_mfma_f32_32x32x16_bf16(lA1, hA0, acc10, 0, 0, 0);
      acc10 = __builtin_amdgcn_mfma_f32_32x32x16_bf16(lA1, lA0, acc10, 0, 0, 0);
      acc11 = __builtin_amdgcn_mfma_f32_32x32x16_bf16(hA1, hA1, acc11, 0, 0, 0);
      acc11 = __builtin_amdgcn_mfma_f32_32x32x16_bf16(hA1, lA1, acc11, 0, 0, 0);
      acc11 = __builtin_amdgcn_mfma_f32_32x32x16_bf16(lA1, hA1, acc11, 0, 0, 0);
      acc11 = __builtin_amdgcn_mfma_f32_32x32x16_bf16(lA1, lA1, acc11, 0, 0, 0);
    }
  };

  // hand-unrolled pipeline: LOAD(c+1) issues before COMPUTE(c) (T14)
  LOADC(buf0, 0); CVTW(buf0); __syncthreads();
  LOADC(buf1, 1); COMPUTE(); __syncthreads(); CVTW(buf1); __syncthreads();
  LOADC(buf0, 2); COMPUTE(); __syncthreads(); CVTW(buf0); __syncthreads();
  LOADC(buf1, 3); COMPUTE(); __syncthreads(); CVTW(buf1); __syncthreads();
  LOADC(buf0, 4); COMPUTE(); __syncthreads(); CVTW(buf0); __syncthreads();
  LOADC(buf1, 5); COMPUTE(); __syncthreads(); CVTW(buf1); __syncthreads();
  LOADC(buf0, 6); COMPUTE(); __syncthreads(); CVTW(buf0); __syncthreads();
  LOADC(buf1, 7); COMPUTE(); __syncthreads(); CVTW(buf1); __syncthreads();
  COMPUTE();
  __syncthreads();  // all LDS reads done; buffer about to be repurposed

  // 2-stage fold of 4 wave-partials in the 32 KB LDS (8192 floats exactly):
  // stage A: waves 0,1 write their 64x64 tile; stage B: waves 2,3 add theirs.
  float* R0 = (float*)LDSbuf;          // 4096 floats
  float* R1 = R0 + 4096;               // 4096 floats
  const int coff  = l & 31;
  const int rbase = 4 * (l >> 5);
  float* Rw = (w & 1) ? R1 : R0;
  if (w < 2) {
#pragma unroll
    for (int e = 0; e < 16; e++) {
      const int ri = (e & 3) + 8 * (e >> 2) + rbase;   // C/D row map [m74/m101]
      Rw[ri * 64 + coff]             = acc00[e];
      Rw[ri * 64 + 32 + coff]        = acc01[e];
      Rw[(32 + ri) * 64 + coff]      = acc10[e];
      Rw[(32 + ri) * 64 + 32 + coff] = acc11[e];
    }
  }
  __syncthreads();
  if (w >= 2) {
#pragma unroll
    for (int e = 0; e < 16; e++) {
      const int ri = (e & 3) + 8 * (e >> 2) + rbase;
      Rw[ri * 64 + coff]             += acc00[e];
      Rw[ri * 64 + 32 + coff]        += acc01[e];
      Rw[(32 + ri) * 64 + coff]      += acc10[e];
      Rw[(32 + ri) * 64 + 32 + coff] += acc11[e];
    }
  }
  __syncthreads();
  float* P = Spart + (size_t)blockIdx.x * 4096;
  for (int idx = t; idx < 4096; idx += 256)
    P[idx] = R0[idx] + R1[idx];

  // chansum: per-thread fp32 row partial -> 4-lane shfl fold -> one atomic
  float s = psum;
  s += __shfl_down(s, 2);
  s += __shfl_down(s, 1);
  if ((t & 3) == 0) atomicAdd(&chansum[g * 64 + row], s);
}

// ---------------------------------------------------------------------------
// K2: fold 64 partial tiles per group into S. 128 blocks x 256 thr.
// Single owner per entry -> plain store, no atomics, S needs no pre-zeroing.
// ---------------------------------------------------------------------------
__global__ __launch_bounds__(256) void reduce_kernel(const float* __restrict__ Spart,
                                                     float* __restrict__ S) {
  const int idx = blockIdx.x * 256 + threadIdx.x;  // 0..32767
  const int g   = idx >> 12;
  const int e   = idx & 4095;
  const float* P = Spart + ((size_t)(g * 64)) * 4096 + e;
  float s = 0.f;
#pragma unroll 8
  for (int p = 0; p < 64; p++) s += P[(size_t)p * 4096];
  S[idx] = s;
}

// ---------------------------------------------------------------------------
// K3: per-group top eigenpair of cov = S/M - mu muT + eps I.
// 12 in-place trace-normalized squarings of (C - sigma I) in fp32 LDS
// (4x4 register tiles, conflict-free), fp64 power polish + Rayleigh.
// 8 blocks x 256 threads (round-0 full-tile version, unchanged).
// ---------------------------------------------------------------------------
__global__ __launch_bounds__(256) void eigen_kernel(
    const float* __restrict__ S, const float* __restrict__ chansum,
    const float* __restrict__ weight, const float* __restrict__ bias,
    float* __restrict__ v0f, float* __restrict__ w2, float* __restrict__ b2) {
  const int g = blockIdx.x;
  __shared__ __align__(16) float Bf[64 * 68];  // 17408 B, stride 68
  __shared__ double Cd[64][65];                // 33280 B
  __shared__ double vv[64], uu[64];
  __shared__ double dred;
  __shared__ float f32red;
  __shared__ int ired;
  const int t  = threadIdx.x;
  const int ti = t >> 4, tj = t & 15;
  const double Minv = 1.0 / 65536.0;

  for (int idx = t; idx < 4096; idx += 256) {
    const int i = idx >> 6, j = idx & 63;
    const double mui = (double)chansum[g * 64 + i] * Minv;
    const double muj = (double)chansum[g * 64 + j] * Minv;
    Cd[i][j] = (double)S[g * 4096 + idx] * Minv - mui * muj + (i == j ? 1e-4 : 0.0);
  }
  __syncthreads();
  if (t < 64) {  // PSD-safe shift: sigma = 0.49 * min(diag) <= 0.49*lam_min... < lam1/2
    double d = Cd[t][t];
#pragma unroll
    for (int off = 32; off; off >>= 1) d = fmin(d, __shfl_down(d, off));
    if (t == 0) f32red = (float)(0.49 * fmax(d, 0.0));
  }
  __syncthreads();
  const float sg = f32red;
  for (int idx = t; idx < 4096; idx += 256) {
    const int i = idx >> 6, j = idx & 63;
    Bf[i * 68 + j] = (float)Cd[i][j] - (i == j ? sg : 0.f);
  }
  __syncthreads();

  for (int it = 0; it < 12; it++) {
    if (t < 64) {
      float tr = Bf[t * 68 + t];
#pragma unroll
      for (int off = 32; off; off >>= 1) tr += __shfl_down(tr, off);
      if (t == 0) f32red = 1.f / tr;
    }
    __syncthreads();
    const float sc = f32red, scl = sc * sc;
    float acc[4][4];
#pragma unroll
    for (int r = 0; r < 4; r++)
#pragma unroll
      for (int s = 0; s < 4; s++) acc[r][s] = 0.f;
#pragma unroll 16
    for (int kk = 0; kk < 64; kk++) {  // B symmetric: rows == cols
      const float4 a = *(const float4*)&Bf[kk * 68 + 4 * ti];
      const float4 b = *(const float4*)&Bf[kk * 68 + 4 * tj];
      acc[0][0] += a.x * b.x; acc[0][1] += a.x * b.y; acc[0][2] += a.x * b.z; acc[0][3] += a.x * b.w;
      acc[1][0] += a.y * b.x; acc[1][1] += a.y * b.y; acc[1][2] += a.y * b.z; acc[1][3] += a.y * b.w;
      acc[2][0] += a.z * b.x; acc[2][1] += a.z * b.y; acc[2][2] += a.z * b.z; acc[2][3] += a.z * b.w;
      acc[3][0] += a.w * b.x; acc[3][1] += a.w * b.y; acc[3][2] += a.w * b.z; acc[3][3] += a.w * b.w;
    }
    __syncthreads();
#pragma unroll
    for (int r = 0; r < 4; r++) {
      float4 w4;
      w4.x = acc[r][0] * scl; w4.y = acc[r][1] * scl;
      w4.z = acc[r][2] * scl; w4.w = acc[r][3] * scl;
      *(float4*)&Bf[(4 * ti + r) * 68 + 4 * tj] = w4;
    }
    __syncthreads();
  }

  // dominant eigvec ~ column jstar of B^(2^12), jstar = argmax diag
  if (t < 64) {
    float d = Bf[t * 68 + t];
    int bj = t;
#pragma unroll
    for (int off = 32; off; off >>= 1) {
      const float od = __shfl_down(d, off);
      const int   oj = __shfl_down(bj, off);
      if (od > d) { d = od; bj = oj; }
    }
    if (t == 0) ired = bj;
  }
  __syncthreads();
  const int jstar = ired;
  if (t < 64) vv[t] = (double)Bf[t * 68 + jstar];
  __syncthreads();

  for (int pi = 0; pi < 3; pi++) {  // fp64 power polish
    if (t < 64) {
      double s = 0.0;
      for (int k = 0; k < 64; k++) s += Cd[t][k] * vv[k];
      uu[t] = s;
    }
    __syncthreads();
    if (t < 64) {
      double q = uu[t] * uu[t];
#pragma unroll
      for (int off = 32; off; off >>= 1) q += __shfl_down(q, off);
      if (t == 0) dred = 1.0 / sqrt(q);
    }
    __syncthreads();
    if (t < 64) vv[t] = uu[t] * dred;
    __syncthreads();
  }
  if (t < 64) {  // Rayleigh quotient
    double s = 0.0;
    for (int k = 0; k < 64; k++) s += Cd[t][k] * vv[k];
    uu[t] = s;
  }
  __syncthreads();
  if (t < 64) {
    double q = vv[t] * uu[t];
#pragma unroll
    for (int off = 32; off; off >>= 1) q += __shfl_down(q, off);
    if (t == 0) dred = 1.0 / sqrt(q);  // rsqrt(lam1)
  }
  __syncthreads();
  const double rsl = dred;
  double w2v = 0.0;
  if (t < 64) {
    const int c = g * 64 + t;
    v0f[c] = (float)vv[t];
    w2v = (double)weight[c] * rsl * vv[t];
    w2[c] = (float)w2v;
  }
  __syncthreads();
  if (t < 64) {  // d0 = v0 . mu, fold into bias
    double q = vv[t] * ((double)chansum[g * 64 + t] * Minv);
#pragma unroll
    for (int off = 32; off; off >>= 1) q += __shfl_down(q, off);
    if (t == 0) dred = q;
  }
  __syncthreads();
  if (t < 64) {
    const int c = g * 64 + t;
    b2[c] = (float)((double)bias[c] - w2v * dred);
  }
}

// ---------------------------------------------------------------------------
// K4: out[c][col] = w2[c] * (v0 . x[:,col]) + b2[c].  2048 blocks x 256 thr,
// one column/thread, coalesced 256B scalar transactions (round-0 version).
// ---------------------------------------------------------------------------
__global__ __launch_bounds__(256, 8) void apply_kernel(
    const float* __restrict__ x, const float* __restrict__ v0f,
    const float* __restrict__ w2, const float* __restrict__ b2,
    float* __restrict__ out) {
  const int q = blockIdx.x & 3;
  const int n = (blockIdx.x >> 2) & 63;
  const int g = blockIdx.x >> 8;
  __shared__ float vs[64], wsh[64], bsh[64];
  const int t = threadIdx.x;
  if (t < 64) {
    vs[t]  = v0f[g * 64 + t];
    wsh[t] = w2[g * 64 + t];
    bsh[t] = b2[g * 64 + t];
  }
  __syncthreads();
  const size_t boff = ((size_t)(n * C_CH + g * 64)) * HW + q * 256 + t;
  const float* base = x + boff;
  float p = 0.f;
#pragma unroll 8
  for (int l = 0; l < 64; l++) p += vs[l] * base[(size_t)l * HW];
  float* ob = out + boff;
#pragma unroll 8
  for (int l = 0; l < 64; l++) ob[(size_t)l * HW] = wsh[l] * p + bsh[l];
}

extern "C" void kernel_launch(void* const* d_in, const int* in_sizes, int n_in,
                              void* d_out, int out_size, void* d_ws, size_t ws_size,
                              hipStream_t stream) {
  const float* x      = (const float*)d_in[0];
  const float* weight = (const float*)d_in[1];
  const float* bias   = (const float*)d_in[2];
  float* out = (float*)d_out;
  float* ws  = (float*)d_ws;

  float* S       = ws;            // 32768 (fully written by reduce_kernel)
  float* chansum = ws + 32768;    // 512 (atomically accumulated -> zero it)
  float* v0f     = ws + 33280;    // 512
  float* w2      = ws + 33792;    // 512
  float* b2      = ws + 34304;    // 512
  float* Spart   = out;           // d_out as scratch: 512*4096 floats (8.4 MB)

  hipMemsetAsync((char*)d_ws + 32768 * sizeof(float), 0, 512 * sizeof(float), stream);

  cov_kernel<<<dim3(512), dim3(256), 0, stream>>>(x, Spart, chansum);
  reduce_kernel<<<dim3(128), dim3(256), 0, stream>>>(Spart, S);
  eigen_kernel<<<dim3(8), dim3(256), 0, stream>>>(S, chansum, weight, bias,
                                                  v0f, w2, b2);
  apply_kernel<<<dim3(2048), dim3(256), 0, stream>>>(x, v0f, w2, b2, out);
}

// Round 6
// 329.815 us; speedup vs baseline: 1.2561x; 1.2561x over previous
//
#include <hip/hip_runtime.h>

#define HW    1024
#define C_CH  512

typedef __attribute__((ext_vector_type(8)))  short bfrag;    // 8 bf16 = 4 VGPR (MFMA A/B operand)
typedef __attribute__((ext_vector_type(16))) float f32x16;   // MFMA 32x32 accumulator

// ws layout (floats): S[8][4096] @0 (fully written by reduce, no zeroing),
//                     chansum[512] @32768 (zeroed), v0f[512] @33280,
//                     w2[512] @33792, b2[512] @34304
// d_out doubles as scratch for cov partial tiles: Spart[512][4096] (8.4 MB),
// consumed by reduce_kernel BEFORE apply_kernel overwrites d_out.

// ---------------------------------------------------------------------------
// K1: per-(g,n) Gram of a 64ch x 1024hw slab via split-bf16 MFMA.
// Identical to the round-4 kernel that ran and validated (absmax unchanged),
// with ONE change: staging uses straight-line NAMED float4 registers and a
// by-value convert helper instead of pointer-passed float4 arrays. The
// arrays were addressable -> allocated in scratch -> 172 MB of spill
// traffic (rocprof WRITE_SIZE). Named regs cannot spill that way.
// fp32 x = hi + lo (RNE bf16 each; lo exact by Sterbenz); Gram sums 4 passes
// hh+hl+lh+ll of mfma_f32_32x32x16_bf16. A-frag == B-frag for a Gram
// (row=lane&31, k=8*(lane>>5)+e) -> 4 ds_read_b128 feed 16 MFMAs per k-step.
// 512 blocks x 256 thr; 8 chunks x 128 cols; 32 KB LDS (bf16 hi+lo),
// 16B-slot XOR swizzle slot^(row&7) -> conflict-free frag reads.
// ---------------------------------------------------------------------------
__global__ __launch_bounds__(256, 2) void cov_kernel(const float* __restrict__ x,
                                                     float* __restrict__ Spart,
                                                     float* __restrict__ chansum) {
  const int n = blockIdx.x & 63;
  const int g = blockIdx.x >> 6;
  __shared__ __align__(16) unsigned short LDSbuf[2 * 64 * 128];  // 32 KB
  unsigned short* Ahi = LDSbuf;
  unsigned short* Alo = LDSbuf + 64 * 128;

  const int t   = threadIdx.x;
  const int row = t >> 2;    // staging channel 0..63
  const int kq  = t & 3;     // staging col-quarter within a 128-col chunk
  const int l   = t & 63;    // lane
  const int w   = t >> 6;    // wave

  const float* rowp = x + ((size_t)(n * C_CH + g * 64) + row) * HW + kq * 32;

  f32x16 acc00 = {}, acc01 = {}, acc10 = {}, acc11 = {};
  float psum = 0.f;

  // split-convert 8 floats (two float4s BY VALUE) -> one 16B hi + lo slot
  auto cvt8 = [&](float4 a, float4 b, int p) {
    const float xv[8] = {a.x, a.y, a.z, a.w, b.x, b.y, b.z, b.w};
    unsigned int hu[8], lw[8];
#pragma unroll
    for (int e = 0; e < 8; e++) {
      const float xf = xv[e];
      const unsigned int u  = __float_as_uint(xf);
      const unsigned int r  = u + 0x7FFFu + ((u >> 16) & 1u);   // RNE to bf16
      const unsigned int hb = r & 0xFFFF0000u;
      const float lof = xf - __uint_as_float(hb);               // exact (Sterbenz)
      const unsigned int v  = __float_as_uint(lof);
      const unsigned int lr = v + 0x7FFFu + ((v >> 16) & 1u);   // RNE to bf16
      hu[e] = hb >> 16;
      lw[e] = lr >> 16;
      psum += xf;
    }
    uint4 hp, lp;
    hp.x = hu[0] | (hu[1] << 16); hp.y = hu[2] | (hu[3] << 16);
    hp.z = hu[4] | (hu[5] << 16); hp.w = hu[6] | (hu[7] << 16);
    lp.x = lw[0] | (lw[1] << 16); lp.y = lw[2] | (lw[3] << 16);
    lp.z = lw[4] | (lw[5] << 16); lp.w = lw[6] | (lw[7] << 16);
    const int slot = (kq * 4 + p) ^ (row & 7);  // 16 slots/row, XOR-swizzled
    *(uint4*)&Ahi[row * 128 + slot * 8] = hp;
    *(uint4*)&Alo[row * 128 + slot * 8] = lp;
  };

  auto compute = [&]() {
#pragma unroll
    for (int k4 = 0; k4 < 2; k4++) {
      const int kl = w * 2 + k4;                // local k-step 0..7 (16 k each)
      const int sp = kl * 2 + (l >> 5);         // 16B slot index along k, 0..15
      const int r0 = l & 31;
      const int ph = sp ^ (r0 & 7);             // (32+r0)&7 == r0&7
      const int i0 = r0 * 128 + ph * 8;
      const int i1 = (32 + r0) * 128 + ph * 8;
      const bfrag hA0 = *(const bfrag*)&Ahi[i0];
      const bfrag hA1 = *(const bfrag*)&Ahi[i1];
      const bfrag lA0 = *(const bfrag*)&Alo[i0];
      const bfrag lA1 = *(const bfrag*)&Alo[i1];
      acc00 = __builtin_amdgcn_mfma_f32_32x32x16_bf16(hA0, hA0, acc00, 0, 0, 0);
      acc00 = __builtin_amdgcn_mfma_f32_32x32x16_bf16(hA0, lA0, acc00, 0, 0, 0);
      acc00 = __builtin_amdgcn_mfma_f32_32x32x16_bf16(lA0, hA0, acc00, 0, 0, 0);
      acc00 = __builtin_amdgcn_mfma_f32_32x32x16_bf16(lA0, lA0, acc00, 0, 0, 0);
      acc01 = __builtin_amdgcn_mfma_f32_32x32x16_bf16(hA0, hA1, acc01, 0, 0, 0);
      acc01 = __builtin_amdgcn_mfma_f32_32x32x16_bf16(hA0, lA1, acc01, 0, 0, 0);
      acc01 = __builtin_amdgcn_mfma_f32_32x32x16_bf16(lA0, hA1, acc01, 0, 0, 0);
      acc01 = __builtin_amdgcn_mfma_f32_32x32x16_bf16(lA0, lA1, acc01, 0, 0, 0);
      acc10 = __builtin_amdgcn_mfma_f32_32x32x16_bf16(hA1, hA0, acc10, 0, 0, 0);
      acc10 = __builtin_amdgcn_mfma_f32_32x32x16_bf16(hA1, lA0, acc10, 0, 0, 0);
      acc10 = __builtin_amdgcn_mfma_f32_32x32x16_bf16(lA1, hA0, acc10, 0, 0, 0);
      acc10 = __builtin_amdgcn_mfma_f32_32x32x16_bf16(lA1, lA0, acc10, 0, 0, 0);
      acc11 = __builtin_amdgcn_mfma_f32_32x32x16_bf16(hA1, hA1, acc11, 0, 0, 0);
      acc11 = __builtin_amdgcn_mfma_f32_32x32x16_bf16(hA1, lA1, acc11, 0, 0, 0);
      acc11 = __builtin_amdgcn_mfma_f32_32x32x16_bf16(lA1, hA1, acc11, 0, 0, 0);
      acc11 = __builtin_amdgcn_mfma_f32_32x32x16_bf16(lA1, lA1, acc11, 0, 0, 0);
    }
  };

  for (int c = 0; c < 8; ++c) {
    const float* cp = rowp + c * 128;
    const float4 v0 = *(const float4*)(cp + 0);
    const float4 v1 = *(const float4*)(cp + 4);
    const float4 v2 = *(const float4*)(cp + 8);
    const float4 v3 = *(const float4*)(cp + 12);
    const float4 v4 = *(const float4*)(cp + 16);
    const float4 v5 = *(const float4*)(cp + 20);
    const float4 v6 = *(const float4*)(cp + 24);
    const float4 v7 = *(const float4*)(cp + 28);
    cvt8(v0, v1, 0);
    cvt8(v2, v3, 1);
    cvt8(v4, v5, 2);
    cvt8(v6, v7, 3);
    __syncthreads();
    compute();
    __syncthreads();
  }

  // 2-stage fold of 4 wave-partials in the 32 KB LDS (8192 floats exactly):
  // stage A: waves 0,1 write their 64x64 tile; stage B: waves 2,3 add theirs.
  float* R0 = (float*)LDSbuf;          // 4096 floats
  float* R1 = R0 + 4096;               // 4096 floats
  const int coff  = l & 31;
  const int rbase = 4 * (l >> 5);
  float* Rw = (w & 1) ? R1 : R0;
  if (w < 2) {
#pragma unroll
    for (int e = 0; e < 16; e++) {
      const int ri = (e & 3) + 8 * (e >> 2) + rbase;   // C/D row map [m74/m101]
      Rw[ri * 64 + coff]             = acc00[e];
      Rw[ri * 64 + 32 + coff]        = acc01[e];
      Rw[(32 + ri) * 64 + coff]      = acc10[e];
      Rw[(32 + ri) * 64 + 32 + coff] = acc11[e];
    }
  }
  __syncthreads();
  if (w >= 2) {
#pragma unroll
    for (int e = 0; e < 16; e++) {
      const int ri = (e & 3) + 8 * (e >> 2) + rbase;
      Rw[ri * 64 + coff]             += acc00[e];
      Rw[ri * 64 + 32 + coff]        += acc01[e];
      Rw[(32 + ri) * 64 + coff]      += acc10[e];
      Rw[(32 + ri) * 64 + 32 + coff] += acc11[e];
    }
  }
  __syncthreads();
  float* P = Spart + (size_t)blockIdx.x * 4096;
  for (int idx = t; idx < 4096; idx += 256)
    P[idx] = R0[idx] + R1[idx];

  // chansum: per-thread fp32 row partial -> 4-lane shfl fold -> one atomic
  float s = psum;
  s += __shfl_down(s, 2);
  s += __shfl_down(s, 1);
  if ((t & 3) == 0) atomicAdd(&chansum[g * 64 + row], s);
}

// ---------------------------------------------------------------------------
// K2: fold 64 partial tiles per group into S. 128 blocks x 256 thr.
// Single owner per entry -> plain store, no atomics, S needs no pre-zeroing.
// ---------------------------------------------------------------------------
__global__ __launch_bounds__(256) void reduce_kernel(const float* __restrict__ Spart,
                                                     float* __restrict__ S) {
  const int idx = blockIdx.x * 256 + threadIdx.x;  // 0..32767
  const int g   = idx >> 12;
  const int e   = idx & 4095;
  const float* P = Spart + ((size_t)(g * 64)) * 4096 + e;
  float s = 0.f;
#pragma unroll 8
  for (int p = 0; p < 64; p++) s += P[(size_t)p * 4096];
  S[idx] = s;
}

// ---------------------------------------------------------------------------
// K3: per-group top eigenpair of cov = S/M - mu muT + eps I.
// 12 in-place trace-normalized squarings of (C - sigma I) in fp32 LDS
// (4x4 register tiles, conflict-free), fp64 power polish + Rayleigh.
// 8 blocks x 256 threads (round-0 full-tile version, unchanged).
// ---------------------------------------------------------------------------
__global__ __launch_bounds__(256) void eigen_kernel(
    const float* __restrict__ S, const float* __restrict__ chansum,
    const float* __restrict__ weight, const float* __restrict__ bias,
    float* __restrict__ v0f, float* __restrict__ w2, float* __restrict__ b2) {
  const int g = blockIdx.x;
  __shared__ __align__(16) float Bf[64 * 68];  // 17408 B, stride 68
  __shared__ double Cd[64][65];                // 33280 B
  __shared__ double vv[64], uu[64];
  __shared__ double dred;
  __shared__ float f32red;
  __shared__ int ired;
  const int t  = threadIdx.x;
  const int ti = t >> 4, tj = t & 15;
  const double Minv = 1.0 / 65536.0;

  for (int idx = t; idx < 4096; idx += 256) {
    const int i = idx >> 6, j = idx & 63;
    const double mui = (double)chansum[g * 64 + i] * Minv;
    const double muj = (double)chansum[g * 64 + j] * Minv;
    Cd[i][j] = (double)S[g * 4096 + idx] * Minv - mui * muj + (i == j ? 1e-4 : 0.0);
  }
  __syncthreads();
  if (t < 64) {  // PSD-safe shift: sigma = 0.49 * min(diag) <= 0.49*lam_min... < lam1/2
    double d = Cd[t][t];
#pragma unroll
    for (int off = 32; off; off >>= 1) d = fmin(d, __shfl_down(d, off));
    if (t == 0) f32red = (float)(0.49 * fmax(d, 0.0));
  }
  __syncthreads();
  const float sg = f32red;
  for (int idx = t; idx < 4096; idx += 256) {
    const int i = idx >> 6, j = idx & 63;
    Bf[i * 68 + j] = (float)Cd[i][j] - (i == j ? sg : 0.f);
  }
  __syncthreads();

  for (int it = 0; it < 12; it++) {
    if (t < 64) {
      float tr = Bf[t * 68 + t];
#pragma unroll
      for (int off = 32; off; off >>= 1) tr += __shfl_down(tr, off);
      if (t == 0) f32red = 1.f / tr;
    }
    __syncthreads();
    const float sc = f32red, scl = sc * sc;
    float acc[4][4];
#pragma unroll
    for (int r = 0; r < 4; r++)
#pragma unroll
      for (int s = 0; s < 4; s++) acc[r][s] = 0.f;
#pragma unroll 16
    for (int kk = 0; kk < 64; kk++) {  // B symmetric: rows == cols
      const float4 a = *(const float4*)&Bf[kk * 68 + 4 * ti];
      const float4 b = *(const float4*)&Bf[kk * 68 + 4 * tj];
      acc[0][0] += a.x * b.x; acc[0][1] += a.x * b.y; acc[0][2] += a.x * b.z; acc[0][3] += a.x * b.w;
      acc[1][0] += a.y * b.x; acc[1][1] += a.y * b.y; acc[1][2] += a.y * b.z; acc[1][3] += a.y * b.w;
      acc[2][0] += a.z * b.x; acc[2][1] += a.z * b.y; acc[2][2] += a.z * b.z; acc[2][3] += a.z * b.w;
      acc[3][0] += a.w * b.x; acc[3][1] += a.w * b.y; acc[3][2] += a.w * b.z; acc[3][3] += a.w * b.w;
    }
    __syncthreads();
#pragma unroll
    for (int r = 0; r < 4; r++) {
      float4 w4;
      w4.x = acc[r][0] * scl; w4.y = acc[r][1] * scl;
      w4.z = acc[r][2] * scl; w4.w = acc[r][3] * scl;
      *(float4*)&Bf[(4 * ti + r) * 68 + 4 * tj] = w4;
    }
    __syncthreads();
  }

  // dominant eigvec ~ column jstar of B^(2^12), jstar = argmax diag
  if (t < 64) {
    float d = Bf[t * 68 + t];
    int bj = t;
#pragma unroll
    for (int off = 32; off; off >>= 1) {
      const float od = __shfl_down(d, off);
      const int   oj = __shfl_down(bj, off);
      if (od > d) { d = od; bj = oj; }
    }
    if (t == 0) ired = bj;
  }
  __syncthreads();
  const int jstar = ired;
  if (t < 64) vv[t] = (double)Bf[t * 68 + jstar];
  __syncthreads();

  for (int pi = 0; pi < 3; pi++) {  // fp64 power polish
    if (t < 64) {
      double s = 0.0;
      for (int k = 0; k < 64; k++) s += Cd[t][k] * vv[k];
      uu[t] = s;
    }
    __syncthreads();
    if (t < 64) {
      double q = uu[t] * uu[t];
#pragma unroll
      for (int off = 32; off; off >>= 1) q += __shfl_down(q, off);
      if (t == 0) dred = 1.0 / sqrt(q);
    }
    __syncthreads();
    if (t < 64) vv[t] = uu[t] * dred;
    __syncthreads();
  }
  if (t < 64) {  // Rayleigh quotient
    double s = 0.0;
    for (int k = 0; k < 64; k++) s += Cd[t][k] * vv[k];
    uu[t] = s;
  }
  __syncthreads();
  if (t < 64) {
    double q = vv[t] * uu[t];
#pragma unroll
    for (int off = 32; off; off >>= 1) q += __shfl_down(q, off);
    if (t == 0) dred = 1.0 / sqrt(q);  // rsqrt(lam1)
  }
  __syncthreads();
  const double rsl = dred;
  double w2v = 0.0;
  if (t < 64) {
    const int c = g * 64 + t;
    v0f[c] = (float)vv[t];
    w2v = (double)weight[c] * rsl * vv[t];
    w2[c] = (float)w2v;
  }
  __syncthreads();
  if (t < 64) {  // d0 = v0 . mu, fold into bias
    double q = vv[t] * ((double)chansum[g * 64 + t] * Minv);
#pragma unroll
    for (int off = 32; off; off >>= 1) q += __shfl_down(q, off);
    if (t == 0) dred = q;
  }
  __syncthreads();
  if (t < 64) {
    const int c = g * 64 + t;
    b2[c] = (float)((double)bias[c] - w2v * dred);
  }
}

// ---------------------------------------------------------------------------
// K4: out[c][col] = w2[c] * (v0 . x[:,col]) + b2[c].  2048 blocks x 256 thr,
// one column/thread, coalesced 256B scalar transactions (round-0 version).
// ---------------------------------------------------------------------------
__global__ __launch_bounds__(256, 8) void apply_kernel(
    const float* __restrict__ x, const float* __restrict__ v0f,
    const float* __restrict__ w2, const float* __restrict__ b2,
    float* __restrict__ out) {
  const int q = blockIdx.x & 3;
  const int n = (blockIdx.x >> 2) & 63;
  const int g = blockIdx.x >> 8;
  __shared__ float vs[64], wsh[64], bsh[64];
  const int t = threadIdx.x;
  if (t < 64) {
    vs[t]  = v0f[g * 64 + t];
    wsh[t] = w2[g * 64 + t];
    bsh[t] = b2[g * 64 + t];
  }
  __syncthreads();
  const size_t boff = ((size_t)(n * C_CH + g * 64)) * HW + q * 256 + t;
  const float* base = x + boff;
  float p = 0.f;
#pragma unroll 8
  for (int l = 0; l < 64; l++) p += vs[l] * base[(size_t)l * HW];
  float* ob = out + boff;
#pragma unroll 8
  for (int l = 0; l < 64; l++) ob[(size_t)l * HW] = wsh[l] * p + bsh[l];
}

extern "C" void kernel_launch(void* const* d_in, const int* in_sizes, int n_in,
                              void* d_out, int out_size, void* d_ws, size_t ws_size,
                              hipStream_t stream) {
  const float* x      = (const float*)d_in[0];
  const float* weight = (const float*)d_in[1];
  const float* bias   = (const float*)d_in[2];
  float* out = (float*)d_out;
  float* ws  = (float*)d_ws;

  float* S       = ws;            // 32768 (fully written by reduce_kernel)
  float* chansum = ws + 32768;    // 512 (atomically accumulated -> zero it)
  float* v0f     = ws + 33280;    // 512
  float* w2      = ws + 33792;    // 512
  float* b2      = ws + 34304;    // 512
  float* Spart   = out;           // d_out as scratch: 512*4096 floats (8.4 MB)

  hipMemsetAsync((char*)d_ws + 32768 * sizeof(float), 0, 512 * sizeof(float), stream);

  cov_kernel<<<dim3(512), dim3(256), 0, stream>>>(x, Spart, chansum);
  reduce_kernel<<<dim3(128), dim3(256), 0, stream>>>(Spart, S);
  eigen_kernel<<<dim3(8), dim3(256), 0, stream>>>(S, chansum, weight, bias,
                                                  v0f, w2, b2);
  apply_kernel<<<dim3(2048), dim3(256), 0, stream>>>(x, v0f, w2, b2, out);
}